// Round 9
// baseline (559.541 us; speedup 1.0000x reference)
//
#include <hip/hip_runtime.h>
#include <cstdint>
#include <cmath>

// Problem constants
#define EDIM 1024
#define SEQ 2048
#define BATCH 4
#define NHEAD 16
#define HDIM 64
#define MLPD 4096
#define ROWS 8192  // BATCH*SEQ

typedef unsigned short u16;
typedef __attribute__((ext_vector_type(8))) short short8;   // 8 bf16 = 4 VGPRs (MFMA A/B frag)
typedef __attribute__((ext_vector_type(4))) float floatx4;  // MFMA C/D frag

#define AS1 __attribute__((address_space(1)))
#define AS3 __attribute__((address_space(3)))

// exp(s*0.125) = 2^(s*0.125*log2e); fold scale into Q at GEMM epilogue
#define Q_SCALE 0.18033688011112042f

// s_waitcnt imm (gfx9 encoding): vmcnt[3:0] | expcnt<<4 | lgkmcnt<<8 | vmcnt[5:4]<<14
#define WAITCNT_VM4 0xF74   // vmcnt(4), expcnt/lgkmcnt don't-care
#define WAITCNT_VM0 0xF70   // vmcnt(0)

__device__ __forceinline__ void async16(const void* g, void* l) {
  // 16B-wide global->LDS DMA; LDS dest is wave-uniform base + lane*16
  __builtin_amdgcn_global_load_lds((AS1 void*)g, (AS3 void*)l, 16, 0, 0);
}

__device__ __forceinline__ u16 f2bf(float f) {  // RNE float->bf16
  union { float f; unsigned int u; } v; v.f = f;
  unsigned int u = v.u;
  u += 0x7fffu + ((u >> 16) & 1u);
  return (u16)(u >> 16);
}

__device__ __forceinline__ unsigned int u32of(float f) {
  union { float f; unsigned int u; } v; v.f = f; return v.u;
}

// pack hi16(a)|hi16(b)<<16 in one v_perm_b32 (truncating f32->bf16 pair)
__device__ __forceinline__ unsigned int pack_trunc(float a, float b) {
  return __builtin_amdgcn_perm(u32of(b), u32of(a), 0x07060302u);
}

// native v_exp_f32: computes 2^x
__device__ __forceinline__ float exp2_fast(float x) {
  return __builtin_amdgcn_exp2f(x);
}

// fast GELU (tanh form), ~12 VALU ops, no libm
__device__ __forceinline__ float gelu_f(float x) {
  const float y = 0.7978845608028654f * (x + 0.044715f * x * x * x);
  // tanh(y) = 1 - 2/(1 + 2^(y*2*log2(e)))
  const float e = exp2_fast(y * 2.885390081777927f);
  const float t = 1.0f - 2.0f * __builtin_amdgcn_rcpf(1.0f + e);
  return 0.5f * x * (1.0f + t);
}

// ---------------- all-weights fp32 -> bf16 convert (one launch) ----------------
// Region boundaries are multiples of 1024 elements -> no intra-block divergence.
__global__ __launch_bounds__(256) void cvt_all(const float* __restrict__ a, u16* __restrict__ oa, int na,
                                               const float* __restrict__ b, u16* __restrict__ ob, int nb,
                                               const float* __restrict__ c, u16* __restrict__ oc, int nc,
                                               const float* __restrict__ d, u16* __restrict__ od) {
  int i = (blockIdx.x * 256 + threadIdx.x) * 4;
  const float* src;
  u16* dst;
  if (i < na) { src = a; dst = oa; }
  else if ((i -= na) < nb) { src = b; dst = ob; }
  else if ((i -= nb) < nc) { src = c; dst = oc; }
  else { i -= nc; src = d; dst = od; }
  const float4 v = *(const float4*)(src + i);
  dst[i + 0] = f2bf(v.x); dst[i + 1] = f2bf(v.y);
  dst[i + 2] = f2bf(v.z); dst[i + 3] = f2bf(v.w);
}

// ---------------- LayerNorm (row of 1024) -> bf16 ----------------
__global__ __launch_bounds__(256) void ln_bf16(const float* __restrict__ x,
                                               const float* __restrict__ g,
                                               const float* __restrict__ bta,
                                               u16* __restrict__ outp) {
  const int row = blockIdx.x;
  const int tid = threadIdx.x;
  const float4 v = *(const float4*)(x + (size_t)row * EDIM + tid * 4);
  float s = v.x + v.y + v.z + v.w;
  float ss = v.x * v.x + v.y * v.y + v.z * v.z + v.w * v.w;
#pragma unroll
  for (int o = 1; o < 64; o <<= 1) {
    s += __shfl_xor(s, o);
    ss += __shfl_xor(ss, o);
  }
  __shared__ float red[8];
  const int wave = tid >> 6, lane = tid & 63;
  if (lane == 0) { red[wave] = s; red[4 + wave] = ss; }
  __syncthreads();
  s = red[0] + red[1] + red[2] + red[3];
  ss = red[4] + red[5] + red[6] + red[7];
  const float mu = s * (1.0f / 1024.0f);
  const float var = ss * (1.0f / 1024.0f) - mu * mu;
  const float inv = rsqrtf(var + 1e-5f);
  const float4 gv = *(const float4*)(g + tid * 4);
  const float4 bv = *(const float4*)(bta + tid * 4);
  u16* od = outp + (size_t)row * EDIM + tid * 4;
  od[0] = f2bf((v.x - mu) * inv * gv.x + bv.x);
  od[1] = f2bf((v.y - mu) * inv * gv.y + bv.y);
  od[2] = f2bf((v.z - mu) * inv * gv.z + bv.z);
  od[3] = f2bf((v.w - mu) * inv * gv.w + bv.w);
}

// ---------------- NT GEMM v3: BK=32, double-buffered LDS, raw-barrier pipeline ------
// The m97-structure tax is the s_waitcnt vmcnt(0) drain at every __syncthreads (~1
// memory round-trip per K-iter, measured ~1210 cyc). Here: issue tile i+1's DMA,
// s_waitcnt vmcnt(4) (tile i landed, tile i+1 STAYS IN FLIGHT), raw s_barrier,
// compute tile i, trailing raw s_barrier (buffer-reuse protection, no drain).
// asm memory fences keep LLVM from hoisting the DMA-fed ds_reads (invisible dep).
// EPI: 0 = store fp32
//      1/3 = fp32 store of (acc + bias[col] + res[idx])
//      2 = bf16 store of gelu(acc + bias[col])
//      4 = bf16 store of acc
//      5 = bf16 store of acc * (col<1024 ? Q_SCALE : 1)  (qkv GEMM, prescaled Q)
template <int EPI>
__global__ __launch_bounds__(256) void gemm_bt(const u16* __restrict__ A,
                                               const u16* __restrict__ Bw,
                                               void* __restrict__ Cout,
                                               const float* __restrict__ bias,
                                               const float* __restrict__ res,
                                               int M, int N, int K) {
  __shared__ __align__(16) u16 As[2 * 128 * 32];
  __shared__ __align__(16) u16 Bs[2 * 128 * 32];
  const int tid = threadIdx.x;
  const int lane = tid & 63;
  const int wave = tid >> 6;
  const int quad = lane >> 4;
  const int cl = lane & 15;
  const int row0 = blockIdx.y * 128;
  const int col0 = blockIdx.x * 128;
  const int wm = wave >> 1;  // 2x2 wave grid over 128x128 tile
  const int wn = wave & 1;

  floatx4 acc[4][4];
#pragma unroll
  for (int i = 0; i < 4; ++i)
#pragma unroll
    for (int j = 0; j < 4; ++j) acc[i][j] = (floatx4){0.f, 0.f, 0.f, 0.f};

  // staging (r4 linear layout; its 8-way ds_read conflicts are measured-free):
  // chunk c -> row c>>2, k-chunk c&3; 2 chunks per thread per matrix.
  const int c0 = wave * 64 + lane;
  const int c1 = c0 + 256;
  const u16* Ag0 = A + (size_t)(row0 + (c0 >> 2)) * K + (c0 & 3) * 8;
  const u16* Ag1 = A + (size_t)(row0 + (c1 >> 2)) * K + (c1 & 3) * 8;
  const u16* Bg0 = Bw + (size_t)(col0 + (c0 >> 2)) * K + (c0 & 3) * 8;
  const u16* Bg1 = Bw + (size_t)(col0 + (c1 >> 2)) * K + (c1 & 3) * 8;
  u16* lA0 = As + c0 * 8;
  u16* lA1 = As + c1 * 8;
  u16* lB0 = Bs + c0 * 8;
  u16* lB1 = Bs + c1 * 8;
  const int kfo = quad * 8;
  const int nIter = K >> 5;

  // prologue: stage tile 0 into buffer 0 (4 DMA instrs/wave in flight)
  async16(Ag0, lA0); async16(Ag1, lA1);
  async16(Bg0, lB0); async16(Bg1, lB1);

  for (int i = 0; i < nIter; ++i) {
    const int buf = (i & 1) * 4096;
    if (i + 1 < nIter) {
      const int nbuf = ((i + 1) & 1) * 4096;
      const int k1 = (i + 1) << 5;
      async16(Ag0 + k1, lA0 + nbuf); async16(Ag1 + k1, lA1 + nbuf);
      async16(Bg0 + k1, lB0 + nbuf); async16(Bg1 + k1, lB1 + nbuf);
      __builtin_amdgcn_s_waitcnt(WAITCNT_VM4);  // tile i landed; i+1 in flight
    } else {
      __builtin_amdgcn_s_waitcnt(WAITCNT_VM0);  // last tile: drain
    }
    __builtin_amdgcn_s_barrier();               // all waves' tile-i DMAs landed
    __asm__ volatile("" ::: "memory");          // no hoisting ds_reads above
    short8 af[4], bfr[4];
#pragma unroll
    for (int i4 = 0; i4 < 4; ++i4)
      af[i4] = *(const short8*)(As + buf + (wm * 64 + i4 * 16 + cl) * 32 + kfo);
#pragma unroll
    for (int j = 0; j < 4; ++j)
      bfr[j] = *(const short8*)(Bs + buf + (wn * 64 + j * 16 + cl) * 32 + kfo);
#pragma unroll
    for (int i4 = 0; i4 < 4; ++i4)
#pragma unroll
      for (int j = 0; j < 4; ++j)
        acc[i4][j] = __builtin_amdgcn_mfma_f32_16x16x32_bf16(af[i4], bfr[j], acc[i4][j], 0, 0, 0);
    __asm__ volatile("" ::: "memory");
    __builtin_amdgcn_s_barrier();               // reads done before buf overwrite
  }

  const float qscale = (EPI == 5 && col0 < 1024) ? Q_SCALE : 1.0f;
#pragma unroll
  for (int i = 0; i < 4; ++i) {
#pragma unroll
    for (int r = 0; r < 4; ++r) {
      const int row = row0 + wm * 64 + i * 16 + quad * 4 + r;
#pragma unroll
      for (int j = 0; j < 4; ++j) {
        const int col = col0 + wn * 64 + j * 16 + cl;
        const size_t idx = (size_t)row * N + col;
        float v = acc[i][j][r];
        if (EPI == 0) {
          ((float*)Cout)[idx] = v;
        } else if (EPI == 1 || EPI == 3) {
          ((float*)Cout)[idx] = v + bias[col] + res[idx];
        } else if (EPI == 2) {
          ((u16*)Cout)[idx] = f2bf(gelu_f(v + bias[col]));
        } else if (EPI == 4) {
          ((u16*)Cout)[idx] = f2bf(v);
        } else if (EPI == 5) {
          ((u16*)Cout)[idx] = f2bf(v * qscale);
        }
      }
    }
  }
}

// ---------------- V transpose: qkv bf16 [tok][3072] -> vt[b,h][d][s] bf16 ----------------
__global__ __launch_bounds__(256) void vtrans(const u16* __restrict__ qkv,
                                              u16* __restrict__ vt) {
  __shared__ unsigned int T[64 * 65];
  const int tid = threadIdx.x;
  const int bh = blockIdx.y;
  const int b = bh >> 4;
  const int h = bh & 15;
  const int s0 = blockIdx.x * 64;
#pragma unroll
  for (int pp = 0; pp < 2; ++pp) {
    const int g = pp * 256 + tid;
    const int r = g >> 3;
    const int d0 = (g & 7) * 8;
    const u16* src = qkv + (size_t)(b * SEQ + s0 + r) * 3072 + 2048 + h * 64 + d0;
    short8 v = *(const short8*)src;
#pragma unroll
    for (int i = 0; i < 8; ++i) T[(d0 + i) * 65 + r] = (u16)v[i];
  }
  __syncthreads();
#pragma unroll
  for (int pp = 0; pp < 2; ++pp) {
    const int g = pp * 256 + tid;
    const int d = g >> 3;
    const int sc = (g & 7) * 8;
    short8 v;
#pragma unroll
    for (int i = 0; i < 8; ++i) v[i] = (short)(u16)T[d * 65 + sc + i];
    *(short8*)(vt + ((size_t)bh * 64 + d) * SEQ + s0 + sc) = v;
  }
}

// ---------------- MFMA flash attention v3 ----------------
// Transposed dataflow: S^T = K Q^T, O^T = V^T P^T. Q prescaled by Q_SCALE -> P=exp2(S).
// No-max softmax (scores bounded ~|2|). kv-tile 128 staged per barrier pair,
// consumed as two 64-kv sub-steps. XCD-affine block swizzle.
__global__ __launch_bounds__(256, 4) void attn3(const u16* __restrict__ qkv,
                                                const u16* __restrict__ vt,
                                                u16* __restrict__ outp) {
  __shared__ __align__(16) u16 smem[8192 + 8192 + 4 * 32 * 72];  // Ks | Vs | P (51.2 KB)
  u16* Ks = smem;            // [128 kv][64 d], chunk-swizzled ^(row&7)
  u16* Vs = smem + 8192;     // [64 d][128 kv], chunk-swizzled ^(row&15)
  const int tid = threadIdx.x;
  const int lane = tid & 63;
  const int wave = tid >> 6;
  const int quad = lane >> 4;
  const int cl = lane & 15;

  // XCD-affine swizzle: all 16 q-blocks of one (b,h) on one XCD, adjacent in time
  const int f = blockIdx.y * 16 + blockIdx.x;
  const int xcd = f & 7;
  const int u = f >> 3;
  const int qi = u & 15;
  const int bh = xcd * 8 + (u >> 4);
  const int b = bh >> 4;
  const int h = bh & 15;
  const int q0 = qi * 128;
  u16* Pw = smem + 16384 + wave * (32 * 72);  // P[q=32][kv=64], stride 72

  const u16* qbase = qkv + (size_t)(b * SEQ) * 3072 + h * 64;
  const u16* kbase = qbase + 1024;
  const u16* vbase = vt + (size_t)bh * 64 * SEQ;

  // ---- stage Q tile (128 x 64) swizzled into Ks region ----
#pragma unroll
  for (int p = 0; p < 4; ++p) {
    const int g = (wave * 4 + p) * 64 + lane;
    const int r = g >> 3;
    const int c = (g & 7) ^ (r & 7);
    async16(qbase + (size_t)(q0 + r) * 3072 + c * 8, smem + g * 8);
  }
  __syncthreads();
  short8 qf[2][2];  // B-frag [n=q][k=d]
#pragma unroll
  for (int ng = 0; ng < 2; ++ng)
#pragma unroll
    for (int kc = 0; kc < 2; ++kc) {
      const int row = wave * 32 + ng * 16 + cl;
      qf[ng][kc] = *(const short8*)(smem + row * 64 + (((kc * 4 + quad) ^ (cl & 7)) * 8));
    }

  floatx4 O[4][2];  // [d-group][q-group]
  float lrun[2] = {0.f, 0.f};
#pragma unroll
  for (int mg = 0; mg < 4; ++mg)
#pragma unroll
    for (int ng = 0; ng < 2; ++ng) O[mg][ng] = (floatx4){0.f, 0.f, 0.f, 0.f};

  for (int kt = 0; kt < SEQ / 128; ++kt) {
    const int k0 = kt * 128;
    __syncthreads();  // previous tile consumed (iter 0: qf loaded)
    const u16* kb = kbase + (size_t)k0 * 3072;
#pragma unroll
    for (int p = 0; p < 2; ++p) {
      const int g = wave * 128 + p * 64 + lane;
      const int rk = g >> 3;
      const int ck = (g & 7) ^ (rk & 7);
      async16(kb + (size_t)rk * 3072 + ck * 8, Ks + g * 8);
      const int rv = g >> 4;
      const int cv = (g & 15) ^ (rv & 15);
      async16(vbase + (size_t)rv * SEQ + k0 + cv * 8, Vs + g * 8);
    }
    __syncthreads();  // all tiles landed (vmcnt drained at barrier)

#pragma unroll
    for (int s = 0; s < 2; ++s) {
      // ---- S^T = K Q^T ----
      floatx4 Sc[4][2];
#pragma unroll
      for (int mg = 0; mg < 4; ++mg)
#pragma unroll
        for (int ng = 0; ng < 2; ++ng) Sc[mg][ng] = (floatx4){0.f, 0.f, 0.f, 0.f};
#pragma unroll
      for (int kc = 0; kc < 2; ++kc) {
        short8 kf[4];
#pragma unroll
        for (int mg = 0; mg < 4; ++mg) {
          const int row = s * 64 + mg * 16 + cl;
          kf[mg] = *(const short8*)(Ks + row * 64 + (((kc * 4 + quad) ^ (cl & 7)) * 8));
        }
#pragma unroll
        for (int mg = 0; mg < 4; ++mg)
#pragma unroll
          for (int ng = 0; ng < 2; ++ng)
            Sc[mg][ng] = __builtin_amdgcn_mfma_f32_16x16x32_bf16(kf[mg], qf[ng][kc], Sc[mg][ng], 0, 0, 0);
      }

      // ---- no-max softmax: P = 2^S (Q prescaled); l += sum ----
#pragma unroll
      for (int ng = 0; ng < 2; ++ng) {
        float rs = 0.f;
#pragma unroll
        for (int mg = 0; mg < 4; ++mg)
#pragma unroll
          for (int r = 0; r < 4; ++r) {
            const float pv = exp2_fast(Sc[mg][ng][r]);
            Sc[mg][ng][r] = pv;
            rs += pv;
          }
        rs += __shfl_xor(rs, 16);
        rs += __shfl_xor(rs, 32);
        lrun[ng] += rs;
      }

      // ---- P pack (truncating perm) + b64 store, wave-private ----
#pragma unroll
      for (int mg = 0; mg < 4; ++mg)
#pragma unroll
        for (int ng = 0; ng < 2; ++ng) {
          const unsigned int lo = pack_trunc(Sc[mg][ng][0], Sc[mg][ng][1]);
          const unsigned int hi = pack_trunc(Sc[mg][ng][2], Sc[mg][ng][3]);
          *(uint2*)(Pw + (ng * 16 + cl) * 72 + mg * 16 + quad * 4) = make_uint2(lo, hi);
        }

      // ---- O^T += V^T P^T ----
#pragma unroll
      for (int kc = 0; kc < 2; ++kc) {
        short8 pf[2], vf[4];
#pragma unroll
        for (int ng = 0; ng < 2; ++ng)
          pf[ng] = *(const short8*)(Pw + (ng * 16 + cl) * 72 + kc * 32 + quad * 8);
#pragma unroll
        for (int mg = 0; mg < 4; ++mg) {
          const int row = mg * 16 + cl;
          vf[mg] = *(const short8*)(Vs + row * 128 + (((s * 8 + kc * 4 + quad) ^ (cl & 15)) * 8));
        }
#pragma unroll
        for (int mg = 0; mg < 4; ++mg)
#pragma unroll
          for (int ng = 0; ng < 2; ++ng)
            O[mg][ng] = __builtin_amdgcn_mfma_f32_16x16x32_bf16(vf[mg], pf[ng], O[mg][ng], 0, 0, 0);
      }
    }
  }

  // ---- epilogue: O^T[d][q] / l -> out[q][h*64+d] ----
#pragma unroll
  for (int ng = 0; ng < 2; ++ng) {
    const float inv = 1.0f / lrun[ng];
    const int qrow = q0 + wave * 32 + ng * 16 + cl;
    u16* od = outp + (size_t)(b * SEQ + qrow) * EDIM + h * 64;
#pragma unroll
    for (int mg = 0; mg < 4; ++mg) {
      const unsigned int lo = (unsigned int)f2bf(O[mg][ng][0] * inv) |
                              ((unsigned int)f2bf(O[mg][ng][1] * inv) << 16);
      const unsigned int hi = (unsigned int)f2bf(O[mg][ng][2] * inv) |
                              ((unsigned int)f2bf(O[mg][ng][3] * inv) << 16);
      *(uint2*)(od + mg * 16 + quad * 4) = make_uint2(lo, hi);
    }
  }
}

// ---------------- launcher ----------------
extern "C" void kernel_launch(void* const* d_in, const int* in_sizes, int n_in,
                              void* d_out, int out_size, void* d_ws, size_t ws_size,
                              hipStream_t stream) {
  const float* x    = (const float*)d_in[0];
  const float* qkvw = (const float*)d_in[1];
  const float* fcw  = (const float*)d_in[2];
  const float* fcb  = (const float*)d_in[3];
  const float* ln1g = (const float*)d_in[4];
  const float* ln1b = (const float*)d_in[5];
  const float* ln2g = (const float*)d_in[6];
  const float* ln2b = (const float*)d_in[7];
  const float* w1   = (const float*)d_in[8];
  const float* b1   = (const float*)d_in[9];
  const float* w2   = (const float*)d_in[10];
  const float* b2   = (const float*)d_in[11];

  char* ws = (char*)d_ws;
  size_t off = 0;
  u16* wqkv = (u16*)(ws + off); off += (size_t)3 * EDIM * EDIM * 2;   // 6 MB
  u16* wfc  = (u16*)(ws + off); off += (size_t)EDIM * EDIM * 2;       // 2 MB
  u16* w1b  = (u16*)(ws + off); off += (size_t)MLPD * EDIM * 2;       // 8 MB
  u16* w2b  = (u16*)(ws + off); off += (size_t)EDIM * MLPD * 2;       // 8 MB
  u16* hbuf = (u16*)(ws + off); off += (size_t)ROWS * EDIM * 2;       // 16 MB
  u16* aout = (u16*)(ws + off); off += (size_t)ROWS * EDIM * 2;       // 16 MB
  float* x2 = (float*)(ws + off); off += (size_t)ROWS * EDIM * 4;     // 32 MB
  u16* qkvb = (u16*)(ws + off); off += (size_t)ROWS * 3 * EDIM * 2;   // 48 MB (bf16)
  u16* vtb  = (u16*)(ws + off); off += (size_t)ROWS * EDIM * 2;       // 16 MB
  u16* hmlp = qkvb;  // reuse qkvb+vtb (64 MB) for MLP hidden after attention

  // all weights -> bf16 in one launch (12,582,912 elements / 1024 per block)
  cvt_all<<<12288, 256, 0, stream>>>(qkvw, wqkv, 3 * EDIM * EDIM,
                                     fcw, wfc, EDIM * EDIM,
                                     w1, w1b, MLPD * EDIM,
                                     w2, w2b);

  // attention sublayer
  ln_bf16<<<ROWS, 256, 0, stream>>>(x, ln1g, ln1b, hbuf);
  gemm_bt<5><<<dim3(24, 64), 256, 0, stream>>>(hbuf, wqkv, qkvb, nullptr, nullptr,
                                               ROWS, 3 * EDIM, EDIM);
  vtrans<<<dim3(SEQ / 64, 64), 256, 0, stream>>>(qkvb, vtb);
  attn3<<<dim3(16, 64), 256, 0, stream>>>(qkvb, vtb, aout);
  gemm_bt<1><<<dim3(8, 64), 256, 0, stream>>>(aout, wfc, x2, fcb, x,
                                              ROWS, EDIM, EDIM);
  // MLP sublayer
  ln_bf16<<<ROWS, 256, 0, stream>>>(x2, ln2g, ln2b, hbuf);
  gemm_bt<2><<<dim3(32, 64), 256, 0, stream>>>(hbuf, w1b, hmlp, b1, nullptr,
                                               ROWS, MLPD, EDIM);
  gemm_bt<3><<<dim3(8, 64), 256, 0, stream>>>(hmlp, w2b, (float*)d_out, b2, x2,
                                              ROWS, EDIM, MLPD);
}

// Round 10
// 522.451 us; speedup vs baseline: 1.0710x; 1.0710x over previous
//
#include <hip/hip_runtime.h>
#include <cstdint>
#include <cmath>

// Problem constants
#define EDIM 1024
#define SEQ 2048
#define BATCH 4
#define NHEAD 16
#define HDIM 64
#define MLPD 4096
#define ROWS 8192  // BATCH*SEQ

typedef unsigned short u16;
typedef __attribute__((ext_vector_type(8))) short short8;   // 8 bf16 = 4 VGPRs (MFMA A/B frag)
typedef __attribute__((ext_vector_type(4))) float floatx4;  // MFMA C/D frag

#define AS1 __attribute__((address_space(1)))
#define AS3 __attribute__((address_space(3)))

// exp(s*0.125) = 2^(s*0.125*log2e); fold scale into Q at GEMM epilogue
#define Q_SCALE 0.18033688011112042f

__device__ __forceinline__ void async16(const void* g, void* l) {
  // 16B-wide global->LDS DMA; LDS dest is wave-uniform base + lane*16
  __builtin_amdgcn_global_load_lds((AS1 void*)g, (AS3 void*)l, 16, 0, 0);
}

__device__ __forceinline__ u16 f2bf(float f) {  // RNE float->bf16
  union { float f; unsigned int u; } v; v.f = f;
  unsigned int u = v.u;
  u += 0x7fffu + ((u >> 16) & 1u);
  return (u16)(u >> 16);
}

__device__ __forceinline__ unsigned int u32of(float f) {
  union { float f; unsigned int u; } v; v.f = f; return v.u;
}

// pack hi16(a)|hi16(b)<<16 in one v_perm_b32 (truncating f32->bf16 pair)
__device__ __forceinline__ unsigned int pack_trunc(float a, float b) {
  return __builtin_amdgcn_perm(u32of(b), u32of(a), 0x07060302u);
}

// native v_exp_f32: computes 2^x
__device__ __forceinline__ float exp2_fast(float x) {
  return __builtin_amdgcn_exp2f(x);
}

// fast GELU (tanh form), ~12 VALU ops, no libm
__device__ __forceinline__ float gelu_f(float x) {
  const float y = 0.7978845608028654f * (x + 0.044715f * x * x * x);
  // tanh(y) = 1 - 2/(1 + 2^(y*2*log2(e)))
  const float e = exp2_fast(y * 2.885390081777927f);
  const float t = 1.0f - 2.0f * __builtin_amdgcn_rcpf(1.0f + e);
  return 0.5f * x * (1.0f + t);
}

// ---------------- all-weights fp32 -> bf16 convert (one launch) ----------------
// Region boundaries are multiples of 1024 elements -> no intra-block divergence.
__global__ __launch_bounds__(256) void cvt_all(const float* __restrict__ a, u16* __restrict__ oa, int na,
                                               const float* __restrict__ b, u16* __restrict__ ob, int nb,
                                               const float* __restrict__ c, u16* __restrict__ oc, int nc,
                                               const float* __restrict__ d, u16* __restrict__ od) {
  int i = (blockIdx.x * 256 + threadIdx.x) * 4;
  const float* src;
  u16* dst;
  if (i < na) { src = a; dst = oa; }
  else if ((i -= na) < nb) { src = b; dst = ob; }
  else if ((i -= nb) < nc) { src = c; dst = oc; }
  else { i -= nc; src = d; dst = od; }
  const float4 v = *(const float4*)(src + i);
  dst[i + 0] = f2bf(v.x); dst[i + 1] = f2bf(v.y);
  dst[i + 2] = f2bf(v.z); dst[i + 3] = f2bf(v.w);
}

// ---------------- LayerNorm (row of 1024) -> bf16 ----------------
__global__ __launch_bounds__(256) void ln_bf16(const float* __restrict__ x,
                                               const float* __restrict__ g,
                                               const float* __restrict__ bta,
                                               u16* __restrict__ outp) {
  const int row = blockIdx.x;
  const int tid = threadIdx.x;
  const float4 v = *(const float4*)(x + (size_t)row * EDIM + tid * 4);
  float s = v.x + v.y + v.z + v.w;
  float ss = v.x * v.x + v.y * v.y + v.z * v.z + v.w * v.w;
#pragma unroll
  for (int o = 1; o < 64; o <<= 1) {
    s += __shfl_xor(s, o);
    ss += __shfl_xor(ss, o);
  }
  __shared__ float red[8];
  const int wave = tid >> 6, lane = tid & 63;
  if (lane == 0) { red[wave] = s; red[4 + wave] = ss; }
  __syncthreads();
  s = red[0] + red[1] + red[2] + red[3];
  ss = red[4] + red[5] + red[6] + red[7];
  const float mu = s * (1.0f / 1024.0f);
  const float var = ss * (1.0f / 1024.0f) - mu * mu;
  const float inv = rsqrtf(var + 1e-5f);
  const float4 gv = *(const float4*)(g + tid * 4);
  const float4 bv = *(const float4*)(bta + tid * 4);
  u16* od = outp + (size_t)row * EDIM + tid * 4;
  od[0] = f2bf((v.x - mu) * inv * gv.x + bv.x);
  od[1] = f2bf((v.y - mu) * inv * gv.y + bv.y);
  od[2] = f2bf((v.z - mu) * inv * gv.z + bv.z);
  od[3] = f2bf((v.w - mu) * inv * gv.w + bv.w);
}

// ---------------- NT GEMM v4: 256x128 tile, BK=64, 512 threads (8 waves) -----------
// Latency-event model (R6->R7 validated): time ~ (#blocks/CU) x (K/BK) x ~1 load
// round-trip. BM=256 halves blocks; BK=64 halves iters; each wave keeps the proven
// 64x64 quadrant (acc[4][4], VGPR ~88). LDS 48 KB -> ~2 blocks/CU.
// XOR chunk swizzle (R7-proven): LDS slot s of row r holds global chunk s^(r&7);
// frag reads 2-way-conflict only.
// EPI: 0 = store fp32
//      1/3 = fp32 store of (acc + bias[col] + res[idx])
//      2 = bf16 store of gelu(acc + bias[col])
//      4 = bf16 store of acc
//      5 = bf16 store of acc * (col<1024 ? Q_SCALE : 1)  (qkv GEMM, prescaled Q)
template <int EPI>
__global__ __launch_bounds__(512) void gemm_bt(const u16* __restrict__ A,
                                               const u16* __restrict__ Bw,
                                               void* __restrict__ Cout,
                                               const float* __restrict__ bias,
                                               const float* __restrict__ res,
                                               int M, int N, int K) {
  __shared__ __align__(16) u16 As[256 * 64];   // 32 KB
  __shared__ __align__(16) u16 Bs[128 * 64];   // 16 KB
  const int tid = threadIdx.x;
  const int lane = tid & 63;
  const int wave = tid >> 6;      // 0..7
  const int quad = lane >> 4;
  const int cl = lane & 15;
  const int row0 = blockIdx.y * 256;
  const int col0 = blockIdx.x * 128;
  const int wm = wave >> 1;       // 0..3: 64-row band
  const int wn = wave & 1;        // 0..1: 64-col band

  floatx4 acc[4][4];
#pragma unroll
  for (int i = 0; i < 4; ++i)
#pragma unroll
    for (int j = 0; j < 4; ++j) acc[i][j] = (floatx4){0.f, 0.f, 0.f, 0.f};

  // staging: chunk c = p*512 + tid; row = p*64 + (tid>>3); LDS slot = tid&7;
  // global chunk gc = (tid&7) ^ ((tid>>3)&7)  (p-independent since p adds 64 rows).
  const int trow = tid >> 3;               // 0..63
  const int gc = (tid & 7) ^ (trow & 7);
  const u16* Ath = A + (size_t)(row0 + trow) * K + gc * 8;
  const u16* Bth = Bw + (size_t)(col0 + trow) * K + gc * 8;
  u16* lA = As + tid * 8;                  // + p*4096
  u16* lB = Bs + tid * 8;
  const size_t pstride = (size_t)64 * K;   // 64 rows per p

  for (int k0 = 0; k0 < K; k0 += 64) {
    __syncthreads();
#pragma unroll
    for (int p = 0; p < 4; ++p)
      async16(Ath + p * pstride + k0, lA + p * 4096);
#pragma unroll
    for (int p = 0; p < 2; ++p)
      async16(Bth + p * pstride + k0, lB + p * 4096);
    __syncthreads();
#pragma unroll
    for (int s = 0; s < 2; ++s) {
      const int ko = ((s * 4 + quad) ^ (cl & 7)) * 8;
      short8 af[4], bfr[4];
#pragma unroll
      for (int i = 0; i < 4; ++i)
        af[i] = *(const short8*)(As + (wm * 64 + i * 16 + cl) * 64 + ko);
#pragma unroll
      for (int j = 0; j < 4; ++j)
        bfr[j] = *(const short8*)(Bs + (wn * 64 + j * 16 + cl) * 64 + ko);
#pragma unroll
      for (int i = 0; i < 4; ++i)
#pragma unroll
        for (int j = 0; j < 4; ++j)
          acc[i][j] = __builtin_amdgcn_mfma_f32_16x16x32_bf16(af[i], bfr[j], acc[i][j], 0, 0, 0);
    }
  }

  const float qscale = (EPI == 5 && col0 < 1024) ? Q_SCALE : 1.0f;
#pragma unroll
  for (int i = 0; i < 4; ++i) {
#pragma unroll
    for (int r = 0; r < 4; ++r) {
      const int row = row0 + wm * 64 + i * 16 + quad * 4 + r;
#pragma unroll
      for (int j = 0; j < 4; ++j) {
        const int col = col0 + wn * 64 + j * 16 + cl;
        const size_t idx = (size_t)row * N + col;
        float v = acc[i][j][r];
        if (EPI == 0) {
          ((float*)Cout)[idx] = v;
        } else if (EPI == 1 || EPI == 3) {
          ((float*)Cout)[idx] = v + bias[col] + res[idx];
        } else if (EPI == 2) {
          ((u16*)Cout)[idx] = f2bf(gelu_f(v + bias[col]));
        } else if (EPI == 4) {
          ((u16*)Cout)[idx] = f2bf(v);
        } else if (EPI == 5) {
          ((u16*)Cout)[idx] = f2bf(v * qscale);
        }
      }
    }
  }
}

// ---------------- V transpose: qkv bf16 [tok][3072] -> vt[b,h][d][s] bf16 ----------------
__global__ __launch_bounds__(256) void vtrans(const u16* __restrict__ qkv,
                                              u16* __restrict__ vt) {
  __shared__ unsigned int T[64 * 65];
  const int tid = threadIdx.x;
  const int bh = blockIdx.y;
  const int b = bh >> 4;
  const int h = bh & 15;
  const int s0 = blockIdx.x * 64;
#pragma unroll
  for (int pp = 0; pp < 2; ++pp) {
    const int g = pp * 256 + tid;
    const int r = g >> 3;
    const int d0 = (g & 7) * 8;
    const u16* src = qkv + (size_t)(b * SEQ + s0 + r) * 3072 + 2048 + h * 64 + d0;
    short8 v = *(const short8*)src;
#pragma unroll
    for (int i = 0; i < 8; ++i) T[(d0 + i) * 65 + r] = (u16)v[i];
  }
  __syncthreads();
#pragma unroll
  for (int pp = 0; pp < 2; ++pp) {
    const int g = pp * 256 + tid;
    const int d = g >> 3;
    const int sc = (g & 7) * 8;
    short8 v;
#pragma unroll
    for (int i = 0; i < 8; ++i) v[i] = (short)(u16)T[d * 65 + sc + i];
    *(short8*)(vt + ((size_t)bh * 64 + d) * SEQ + s0 + sc) = v;
  }
}

// ---------------- MFMA flash attention v3 ----------------
// Transposed dataflow: S^T = K Q^T, O^T = V^T P^T. Q prescaled by Q_SCALE -> P=exp2(S).
// No-max softmax (scores bounded ~|2|). kv-tile 128 staged per barrier pair,
// consumed as two 64-kv sub-steps. XCD-affine block swizzle.
__global__ __launch_bounds__(256, 4) void attn3(const u16* __restrict__ qkv,
                                                const u16* __restrict__ vt,
                                                u16* __restrict__ outp) {
  __shared__ __align__(16) u16 smem[8192 + 8192 + 4 * 32 * 72];  // Ks | Vs | P (51.2 KB)
  u16* Ks = smem;            // [128 kv][64 d], chunk-swizzled ^(row&7)
  u16* Vs = smem + 8192;     // [64 d][128 kv], chunk-swizzled ^(row&15)
  const int tid = threadIdx.x;
  const int lane = tid & 63;
  const int wave = tid >> 6;
  const int quad = lane >> 4;
  const int cl = lane & 15;

  // XCD-affine swizzle: all 16 q-blocks of one (b,h) on one XCD, adjacent in time
  const int f = blockIdx.y * 16 + blockIdx.x;
  const int xcd = f & 7;
  const int u = f >> 3;
  const int qi = u & 15;
  const int bh = xcd * 8 + (u >> 4);
  const int b = bh >> 4;
  const int h = bh & 15;
  const int q0 = qi * 128;
  u16* Pw = smem + 16384 + wave * (32 * 72);  // P[q=32][kv=64], stride 72

  const u16* qbase = qkv + (size_t)(b * SEQ) * 3072 + h * 64;
  const u16* kbase = qbase + 1024;
  const u16* vbase = vt + (size_t)bh * 64 * SEQ;

  // ---- stage Q tile (128 x 64) swizzled into Ks region ----
#pragma unroll
  for (int p = 0; p < 4; ++p) {
    const int g = (wave * 4 + p) * 64 + lane;
    const int r = g >> 3;
    const int c = (g & 7) ^ (r & 7);
    async16(qbase + (size_t)(q0 + r) * 3072 + c * 8, smem + g * 8);
  }
  __syncthreads();
  short8 qf[2][2];  // B-frag [n=q][k=d]
#pragma unroll
  for (int ng = 0; ng < 2; ++ng)
#pragma unroll
    for (int kc = 0; kc < 2; ++kc) {
      const int row = wave * 32 + ng * 16 + cl;
      qf[ng][kc] = *(const short8*)(smem + row * 64 + (((kc * 4 + quad) ^ (cl & 7)) * 8));
    }

  floatx4 O[4][2];  // [d-group][q-group]
  float lrun[2] = {0.f, 0.f};
#pragma unroll
  for (int mg = 0; mg < 4; ++mg)
#pragma unroll
    for (int ng = 0; ng < 2; ++ng) O[mg][ng] = (floatx4){0.f, 0.f, 0.f, 0.f};

  for (int kt = 0; kt < SEQ / 128; ++kt) {
    const int k0 = kt * 128;
    __syncthreads();  // previous tile consumed (iter 0: qf loaded)
    const u16* kb = kbase + (size_t)k0 * 3072;
#pragma unroll
    for (int p = 0; p < 2; ++p) {
      const int g = wave * 128 + p * 64 + lane;
      const int rk = g >> 3;
      const int ck = (g & 7) ^ (rk & 7);
      async16(kb + (size_t)rk * 3072 + ck * 8, Ks + g * 8);
      const int rv = g >> 4;
      const int cv = (g & 15) ^ (rv & 15);
      async16(vbase + (size_t)rv * SEQ + k0 + cv * 8, Vs + g * 8);
    }
    __syncthreads();  // all tiles landed (vmcnt drained at barrier)

#pragma unroll
    for (int s = 0; s < 2; ++s) {
      // ---- S^T = K Q^T ----
      floatx4 Sc[4][2];
#pragma unroll
      for (int mg = 0; mg < 4; ++mg)
#pragma unroll
        for (int ng = 0; ng < 2; ++ng) Sc[mg][ng] = (floatx4){0.f, 0.f, 0.f, 0.f};
#pragma unroll
      for (int kc = 0; kc < 2; ++kc) {
        short8 kf[4];
#pragma unroll
        for (int mg = 0; mg < 4; ++mg) {
          const int row = s * 64 + mg * 16 + cl;
          kf[mg] = *(const short8*)(Ks + row * 64 + (((kc * 4 + quad) ^ (cl & 7)) * 8));
        }
#pragma unroll
        for (int mg = 0; mg < 4; ++mg)
#pragma unroll
          for (int ng = 0; ng < 2; ++ng)
            Sc[mg][ng] = __builtin_amdgcn_mfma_f32_16x16x32_bf16(kf[mg], qf[ng][kc], Sc[mg][ng], 0, 0, 0);
      }

      // ---- no-max softmax: P = 2^S (Q prescaled); l += sum ----
#pragma unroll
      for (int ng = 0; ng < 2; ++ng) {
        float rs = 0.f;
#pragma unroll
        for (int mg = 0; mg < 4; ++mg)
#pragma unroll
          for (int r = 0; r < 4; ++r) {
            const float pv = exp2_fast(Sc[mg][ng][r]);
            Sc[mg][ng][r] = pv;
            rs += pv;
          }
        rs += __shfl_xor(rs, 16);
        rs += __shfl_xor(rs, 32);
        lrun[ng] += rs;
      }

      // ---- P pack (truncating perm) + b64 store, wave-private ----
#pragma unroll
      for (int mg = 0; mg < 4; ++mg)
#pragma unroll
        for (int ng = 0; ng < 2; ++ng) {
          const unsigned int lo = pack_trunc(Sc[mg][ng][0], Sc[mg][ng][1]);
          const unsigned int hi = pack_trunc(Sc[mg][ng][2], Sc[mg][ng][3]);
          *(uint2*)(Pw + (ng * 16 + cl) * 72 + mg * 16 + quad * 4) = make_uint2(lo, hi);
        }

      // ---- O^T += V^T P^T ----
#pragma unroll
      for (int kc = 0; kc < 2; ++kc) {
        short8 pf[2], vf[4];
#pragma unroll
        for (int ng = 0; ng < 2; ++ng)
          pf[ng] = *(const short8*)(Pw + (ng * 16 + cl) * 72 + kc * 32 + quad * 8);
#pragma unroll
        for (int mg = 0; mg < 4; ++mg) {
          const int row = mg * 16 + cl;
          vf[mg] = *(const short8*)(Vs + row * 128 + (((s * 8 + kc * 4 + quad) ^ (cl & 15)) * 8));
        }
#pragma unroll
        for (int mg = 0; mg < 4; ++mg)
#pragma unroll
          for (int ng = 0; ng < 2; ++ng)
            O[mg][ng] = __builtin_amdgcn_mfma_f32_16x16x32_bf16(vf[mg], pf[ng], O[mg][ng], 0, 0, 0);
      }
    }
  }

  // ---- epilogue: O^T[d][q] / l -> out[q][h*64+d] ----
#pragma unroll
  for (int ng = 0; ng < 2; ++ng) {
    const float inv = 1.0f / lrun[ng];
    const int qrow = q0 + wave * 32 + ng * 16 + cl;
    u16* od = outp + (size_t)(b * SEQ + qrow) * EDIM + h * 64;
#pragma unroll
    for (int mg = 0; mg < 4; ++mg) {
      const unsigned int lo = (unsigned int)f2bf(O[mg][ng][0] * inv) |
                              ((unsigned int)f2bf(O[mg][ng][1] * inv) << 16);
      const unsigned int hi = (unsigned int)f2bf(O[mg][ng][2] * inv) |
                              ((unsigned int)f2bf(O[mg][ng][3] * inv) << 16);
      *(uint2*)(od + mg * 16 + quad * 4) = make_uint2(lo, hi);
    }
  }
}

// ---------------- launcher ----------------
extern "C" void kernel_launch(void* const* d_in, const int* in_sizes, int n_in,
                              void* d_out, int out_size, void* d_ws, size_t ws_size,
                              hipStream_t stream) {
  const float* x    = (const float*)d_in[0];
  const float* qkvw = (const float*)d_in[1];
  const float* fcw  = (const float*)d_in[2];
  const float* fcb  = (const float*)d_in[3];
  const float* ln1g = (const float*)d_in[4];
  const float* ln1b = (const float*)d_in[5];
  const float* ln2g = (const float*)d_in[6];
  const float* ln2b = (const float*)d_in[7];
  const float* w1   = (const float*)d_in[8];
  const float* b1   = (const float*)d_in[9];
  const float* w2   = (const float*)d_in[10];
  const float* b2   = (const float*)d_in[11];

  char* ws = (char*)d_ws;
  size_t off = 0;
  u16* wqkv = (u16*)(ws + off); off += (size_t)3 * EDIM * EDIM * 2;   // 6 MB
  u16* wfc  = (u16*)(ws + off); off += (size_t)EDIM * EDIM * 2;       // 2 MB
  u16* w1b  = (u16*)(ws + off); off += (size_t)MLPD * EDIM * 2;       // 8 MB
  u16* w2b  = (u16*)(ws + off); off += (size_t)EDIM * MLPD * 2;       // 8 MB
  u16* hbuf = (u16*)(ws + off); off += (size_t)ROWS * EDIM * 2;       // 16 MB
  u16* aout = (u16*)(ws + off); off += (size_t)ROWS * EDIM * 2;       // 16 MB
  float* x2 = (float*)(ws + off); off += (size_t)ROWS * EDIM * 4;     // 32 MB
  u16* qkvb = (u16*)(ws + off); off += (size_t)ROWS * 3 * EDIM * 2;   // 48 MB (bf16)
  u16* vtb  = (u16*)(ws + off); off += (size_t)ROWS * EDIM * 2;       // 16 MB
  u16* hmlp = qkvb;  // reuse qkvb+vtb (64 MB) for MLP hidden after attention

  // all weights -> bf16 in one launch
  cvt_all<<<12288, 256, 0, stream>>>(qkvw, wqkv, 3 * EDIM * EDIM,
                                     fcw, wfc, EDIM * EDIM,
                                     w1, w1b, MLPD * EDIM,
                                     w2, w2b);

  // attention sublayer
  ln_bf16<<<ROWS, 256, 0, stream>>>(x, ln1g, ln1b, hbuf);
  gemm_bt<5><<<dim3(24, 32), 512, 0, stream>>>(hbuf, wqkv, qkvb, nullptr, nullptr,
                                               ROWS, 3 * EDIM, EDIM);
  vtrans<<<dim3(SEQ / 64, 64), 256, 0, stream>>>(qkvb, vtb);
  attn3<<<dim3(16, 64), 256, 0, stream>>>(qkvb, vtb, aout);
  gemm_bt<1><<<dim3(8, 32), 512, 0, stream>>>(aout, wfc, x2, fcb, x,
                                              ROWS, EDIM, EDIM);
  // MLP sublayer
  ln_bf16<<<ROWS, 256, 0, stream>>>(x2, ln2g, ln2b, hbuf);
  gemm_bt<2><<<dim3(32, 32), 512, 0, stream>>>(hbuf, w1b, hmlp, b1, nullptr,
                                               ROWS, MLPD, EDIM);
  gemm_bt<3><<<dim3(8, 32), 512, 0, stream>>>(hmlp, w2b, (float*)d_out, b2, x2,
                                              ROWS, EDIM, MLPD);
}